// Round 1
// baseline (5599.324 us; speedup 1.0000x reference)
//
#include <hip/hip_runtime.h>

// B=8, T=1024, E=768, H=12.
// Split-bf16 MFMA GEMM: fp32 operands split into (hi, lo) bf16 at LDS staging;
// D = Ah*Bh + Al*Bh + Ah*Bl accumulated in fp32 -> ~1e-5 relative accuracy.
// Round 6: 256x128 tile core (4 waves of 128x64) for QKV projections --
// halves LDS-read traffic per flop (reads scale with wave-tile perimeter);
// final projection k-split 6->12 for occupancy.

typedef __bf16 bf16x8 __attribute__((ext_vector_type(8)));
typedef __bf16 bf16x4 __attribute__((ext_vector_type(4)));
typedef float  f32x4  __attribute__((ext_vector_type(4)));

#define PITCH 40   // bf16 per LDS row (32+8): 16B-aligned frag reads, spread banks

// ---------------- 128x128 core (proven; scores, Z, final) ----------------
__device__ __forceinline__ void gemm_core(
    const float* __restrict__ A, const float* __restrict__ B, float* __restrict__ C,
    int K, int lda, int ldb, int ldc,
    long long aShift, long long aHi, int mClip, int mode,
    int mtile, int kChunk, int kChunks, int n0)
{
    __shared__ __bf16 Ahi[128][PITCH];
    __shared__ __bf16 Alo[128][PITCH];
    __shared__ __bf16 Bhi[128][PITCH];   // transposed: Bhi[n][k]
    __shared__ __bf16 Blo[128][PITCH];

    const int tid = threadIdx.x;
    const int m0 = mtile * 128;
    const int lane = tid & 63;
    const int wave = tid >> 6;
    const int wm = (wave & 1) << 6;      // wave's 64x64 quadrant
    const int wn = (wave >> 1) << 6;
    const int lr = lane & 15;
    const int lq = lane >> 4;

    // staging coords
    const int ar0 = tid >> 3;            // A row 0..31 (+32*l)
    const int ak  = (tid & 7) << 2;      // A k-offset 0,4,..,28
    const int nB  = tid & 127;           // B column (one per thread)
    const int kh  = (tid >> 7) << 4;     // B k-half: 0 or 16

    f32x4 acc[4][4] = {};

    const int kLen = K / kChunks;
    const int kBeg = kChunk * kLen;
    const int kEnd = kBeg + kLen;

    float4 rA[4];
    float  rB[16];

    auto loadAB = [&](int k0) {
#pragma unroll
        for (int l = 0; l < 4; ++l) {
            long long aoff = (long long)(m0 + ar0 + l * 32) * lda + (k0 + ak) + aShift;
            float4 v = make_float4(0.f, 0.f, 0.f, 0.f);
            if (aoff >= 0 && aoff < aHi) v = *(const float4*)&A[aoff];
            rA[l] = v;
        }
#pragma unroll
        for (int j = 0; j < 16; ++j)     // lane-coalesced (consecutive nB)
            rB[j] = B[(long long)(k0 + kh + j) * ldb + n0 + nB];
    };

    loadAB(kBeg);

    for (int k0 = kBeg; k0 < kEnd; k0 += 32) {
        // ---- stage A: hi/lo split, row-major, ds_write_b64 ----
#pragma unroll
        for (int l = 0; l < 4; ++l) {
            float4 v = rA[l];
            bf16x4 h, lo;
            h[0] = (__bf16)v.x; h[1] = (__bf16)v.y;
            h[2] = (__bf16)v.z; h[3] = (__bf16)v.w;
            lo[0] = (__bf16)(v.x - (float)h[0]);
            lo[1] = (__bf16)(v.y - (float)h[1]);
            lo[2] = (__bf16)(v.z - (float)h[2]);
            lo[3] = (__bf16)(v.w - (float)h[3]);
            *(bf16x4*)&Ahi[ar0 + l * 32][ak] = h;
            *(bf16x4*)&Alo[ar0 + l * 32][ak] = lo;
        }
        // ---- stage B: hi/lo split, [n][k] layout, ds_write_b128 ----
        {
            bf16x8 bh0, bh1, bl0, bl1;
#pragma unroll
            for (int j = 0; j < 8; ++j) {
                float v0 = rB[j], v1 = rB[j + 8];
                __bf16 h0 = (__bf16)v0, h1 = (__bf16)v1;
                bh0[j] = h0; bl0[j] = (__bf16)(v0 - (float)h0);
                bh1[j] = h1; bl1[j] = (__bf16)(v1 - (float)h1);
            }
            *(bf16x8*)&Bhi[nB][kh]     = bh0;
            *(bf16x8*)&Bhi[nB][kh + 8] = bh1;
            *(bf16x8*)&Blo[nB][kh]     = bl0;
            *(bf16x8*)&Blo[nB][kh + 8] = bl1;
        }
        __syncthreads();

        // prefetch next k-tile while this tile computes
        if (k0 + 32 < kEnd) loadAB(k0 + 32);

        bf16x8 ah[4], al[4];
#pragma unroll
        for (int mi = 0; mi < 4; ++mi) {
            ah[mi] = *(const bf16x8*)&Ahi[wm + (mi << 4) + lr][lq << 3];
            al[mi] = *(const bf16x8*)&Alo[wm + (mi << 4) + lr][lq << 3];
        }
#pragma unroll
        for (int ni = 0; ni < 4; ++ni) {
            bf16x8 bh = *(const bf16x8*)&Bhi[wn + (ni << 4) + lr][lq << 3];
            bf16x8 bl = *(const bf16x8*)&Blo[wn + (ni << 4) + lr][lq << 3];
#pragma unroll
            for (int mi = 0; mi < 4; ++mi) {
                acc[mi][ni] = __builtin_amdgcn_mfma_f32_16x16x32_bf16(ah[mi], bh, acc[mi][ni], 0, 0, 0);
                acc[mi][ni] = __builtin_amdgcn_mfma_f32_16x16x32_bf16(al[mi], bh, acc[mi][ni], 0, 0, 0);
                acc[mi][ni] = __builtin_amdgcn_mfma_f32_16x16x32_bf16(ah[mi], bl, acc[mi][ni], 0, 0, 0);
            }
        }
        __syncthreads();
    }

    // Epilogue: C/D layout col = lane&15, row = (lane>>4)*4 + reg  [m89]
#pragma unroll
    for (int mi = 0; mi < 4; ++mi)
#pragma unroll
        for (int r = 0; r < 4; ++r) {
            int row = m0 + wm + (mi << 4) + (lq << 2) + r;
            if (row < mClip) {
#pragma unroll
                for (int ni = 0; ni < 4; ++ni) {
                    long long off = (long long)row * ldc + n0 + wn + (ni << 4) + lr;
                    float v = acc[mi][ni][r];
                    if (mode == 2)      atomicAdd(&C[off], v);
                    else                C[off] = v;
                }
            }
        }
}

// Generic batched GEMM. grid: (N/128, mTiles*kChunks, batch).
__global__ __launch_bounds__(256, 2)
void gemm_one(const float* __restrict__ A, const float* __restrict__ B,
              float* __restrict__ C,
              int K, int lda, int ldb, int ldc,
              long long sA, long long sB, long long sC,
              long long aShift, long long aHi, int mClip, int mode, int kChunks)
{
    A += (long long)blockIdx.z * sA;
    B += (long long)blockIdx.z * sB;
    C += (long long)blockIdx.z * sC;
    int mtile = blockIdx.y / kChunks;
    int kc    = blockIdx.y % kChunks;
    gemm_core(A, B, C, K, lda, ldb, ldc, aShift, aHi, mClip, mode,
              mtile, kc, kChunks, blockIdx.x * 128);
}

// ---------------- 256x128 core: 4 waves of 128x64 (QKV) ----------------
// LDS reads per flop cut 1.5x vs 64x64 waves (reads scale with wave-tile
// perimeter). mi-half-split: cache 4 of 8 A-fragment pairs at a time to
// stay under 256 VGPR at 2 waves/SIMD. No bounds checks (callers exact).
__device__ __forceinline__ void gemm_core256(
    const float* __restrict__ A, const float* __restrict__ B, float* __restrict__ C,
    int K, int lda, int ldb, int ldc, int mtile, int n0)
{
    __shared__ __bf16 Ahi[256][PITCH];
    __shared__ __bf16 Alo[256][PITCH];
    __shared__ __bf16 Bhi[128][PITCH];   // transposed: Bhi[n][k]
    __shared__ __bf16 Blo[128][PITCH];   // total 61440 B -> 2 blocks/CU

    const int tid  = threadIdx.x;
    const int m0   = mtile * 256;
    const int lane = tid & 63;
    const int wave = tid >> 6;
    const int wm   = (wave >> 1) << 7;   // 0 / 128: wave row-half
    const int wn   = (wave & 1) << 6;    // 0 / 64 : wave col-half
    const int lr   = lane & 15;
    const int lq   = lane >> 4;

    const int ar0 = tid >> 3;            // A row 0..31 (+32*l, l<8)
    const int ak  = (tid & 7) << 2;      // A k-offset 0,4,..,28
    const int nB  = tid & 127;           // B column
    const int kh  = (tid >> 7) << 4;     // B k-half: 0 or 16

    f32x4 acc[8][4] = {};
    float4 rA[8];
    float  rB[16];

    auto loadAB = [&](int k0) {
#pragma unroll
        for (int l = 0; l < 8; ++l)
            rA[l] = *(const float4*)&A[(long long)(m0 + ar0 + l * 32) * lda + (k0 + ak)];
#pragma unroll
        for (int j = 0; j < 16; ++j)     // lane-coalesced (consecutive nB)
            rB[j] = B[(long long)(k0 + kh + j) * ldb + n0 + nB];
    };

    loadAB(0);

    for (int k0 = 0; k0 < K; k0 += 32) {
        // ---- stage A (256 rows): hi/lo split, ds_write_b64 ----
#pragma unroll
        for (int l = 0; l < 8; ++l) {
            float4 v = rA[l];
            bf16x4 h, lo;
            h[0] = (__bf16)v.x; h[1] = (__bf16)v.y;
            h[2] = (__bf16)v.z; h[3] = (__bf16)v.w;
            lo[0] = (__bf16)(v.x - (float)h[0]);
            lo[1] = (__bf16)(v.y - (float)h[1]);
            lo[2] = (__bf16)(v.z - (float)h[2]);
            lo[3] = (__bf16)(v.w - (float)h[3]);
            *(bf16x4*)&Ahi[ar0 + l * 32][ak] = h;
            *(bf16x4*)&Alo[ar0 + l * 32][ak] = lo;
        }
        // ---- stage B: hi/lo split, [n][k] layout, ds_write_b128 ----
        {
            bf16x8 bh0, bh1, bl0, bl1;
#pragma unroll
            for (int j = 0; j < 8; ++j) {
                float v0 = rB[j], v1 = rB[j + 8];
                __bf16 h0 = (__bf16)v0, h1 = (__bf16)v1;
                bh0[j] = h0; bl0[j] = (__bf16)(v0 - (float)h0);
                bh1[j] = h1; bl1[j] = (__bf16)(v1 - (float)h1);
            }
            *(bf16x8*)&Bhi[nB][kh]     = bh0;
            *(bf16x8*)&Bhi[nB][kh + 8] = bh1;
            *(bf16x8*)&Blo[nB][kh]     = bl0;
            *(bf16x8*)&Blo[nB][kh + 8] = bl1;
        }
        __syncthreads();

        if (k0 + 32 < K) loadAB(k0 + 32);   // prefetch next k-tile

#pragma unroll
        for (int half = 0; half < 2; ++half) {
            const int mb = half << 2;        // mi base: 0 or 4
            bf16x8 ah[4], al[4];
#pragma unroll
            for (int mi = 0; mi < 4; ++mi) {
                ah[mi] = *(const bf16x8*)&Ahi[wm + ((mb + mi) << 4) + lr][lq << 3];
                al[mi] = *(const bf16x8*)&Alo[wm + ((mb + mi) << 4) + lr][lq << 3];
            }
#pragma unroll
            for (int ni = 0; ni < 4; ++ni) {
                bf16x8 bh = *(const bf16x8*)&Bhi[wn + (ni << 4) + lr][lq << 3];
                bf16x8 bl = *(const bf16x8*)&Blo[wn + (ni << 4) + lr][lq << 3];
#pragma unroll
                for (int mi = 0; mi < 4; ++mi) {
                    acc[mb + mi][ni] = __builtin_amdgcn_mfma_f32_16x16x32_bf16(ah[mi], bh, acc[mb + mi][ni], 0, 0, 0);
                    acc[mb + mi][ni] = __builtin_amdgcn_mfma_f32_16x16x32_bf16(al[mi], bh, acc[mb + mi][ni], 0, 0, 0);
                    acc[mb + mi][ni] = __builtin_amdgcn_mfma_f32_16x16x32_bf16(ah[mi], bl, acc[mb + mi][ni], 0, 0, 0);
                }
            }
        }
        __syncthreads();
    }

    // Epilogue: C/D layout col = lane&15, row = (lane>>4)*4 + reg  [m89]
#pragma unroll
    for (int mi = 0; mi < 8; ++mi)
#pragma unroll
        for (int r = 0; r < 4; ++r) {
            int row = m0 + wm + (mi << 4) + (lq << 2) + r;
#pragma unroll
            for (int ni = 0; ni < 4; ++ni)
                C[(long long)row * ldc + n0 + wn + (ni << 4) + lr] = acc[mi][ni][r];
        }
}

// Fused QKV projection: grid (N/128, M/256, 3); z selects W / output.
__global__ __launch_bounds__(256, 2)
void gemm_qkv(const float* __restrict__ A,
              const float* __restrict__ B0, const float* __restrict__ B1,
              const float* __restrict__ B2,
              float* __restrict__ C0, float* __restrict__ C1, float* __restrict__ C2,
              int K, int lda, int ldb, int ldc)
{
    const float* Bs = (blockIdx.z == 0) ? B0 : (blockIdx.z == 1) ? B1 : B2;
    float*       Cs = (blockIdx.z == 0) ? C0 : (blockIdx.z == 1) ? C1 : C2;
    gemm_core256(A, Bs, Cs, K, lda, ldb, ldc, blockIdx.y, blockIdx.x * 128);
}

// Column softmax (normalize over QUERY axis = rows), scale applied pre-max.
// grid: (T/64, nb); block 256 = 64 cols x 4 row-segments. In-place fp32.
__global__ __launch_bounds__(256)
void col_softmax(float* __restrict__ S, int T, float scale)
{
    const int tid = threadIdx.x;
    const int jl = tid & 63;
    const int seg = tid >> 6;
    const int j = blockIdx.x * 64 + jl;
    float* Sb = S + (long long)blockIdx.y * T * T;
    const int rps = T >> 2;
    const int r0 = seg * rps;

    float m = -3.4e38f, s = 0.f;
    for (int r = 0; r < rps; ++r) {
        float v = Sb[(long long)(r0 + r) * T + j] * scale;
        float mn = fmaxf(m, v);
        s = s * __expf(m - mn) + __expf(v - mn);
        m = mn;
    }
    __shared__ float sm[4][64], ss[4][64];
    sm[seg][jl] = m;
    ss[seg][jl] = s;
    __syncthreads();
    float mt = -3.4e38f, st = 0.f;
#pragma unroll
    for (int q = 0; q < 4; ++q) {
        float mq = sm[q][jl], sq = ss[q][jl];
        float mn = fmaxf(mt, mq);
        st = st * __expf(mt - mn) + sq * __expf(mq - mn);
        mt = mn;
    }
    const float inv = 1.f / st;
    for (int r = 0; r < rps; ++r) {
        long long off = (long long)(r0 + r) * T + j;
        Sb[off] = __expf(Sb[off] * scale - mt) * inv;
    }
}

extern "C" void kernel_launch(void* const* d_in, const int* in_sizes, int n_in,
                              void* d_out, int out_size, void* d_ws, size_t ws_size,
                              hipStream_t stream)
{
    const float* x  = (const float*)d_in[0];   // (B,T,E)
    const float* WQ = (const float*)d_in[1];   // (H,E,E)
    const float* WK = (const float*)d_in[2];
    const float* WV = (const float*)d_in[3];
    const float* WO = (const float*)d_in[4];   // (H*E, E)
    float* out = (float*)d_out;                // (B,T,E)

    const int B = 8, T = 1024, E = 768, H = 12;
    const long long TE = (long long)T * E;     // 786432
    const long long TT = (long long)T * T;     // 1048576
    const long long HE = (long long)H * E;     // 9216
    const long long BIG = 1LL << 62;
    const int NOCLIP = 1 << 30;

    // Chunking: one slice = Q,K,V,Z (TE each) + S (TT) fp32 = 16 MiB.
    const long long sliceF = 4 * TE + TT;
    long long wsF = (long long)(ws_size / 4);
    int NC = (int)(wsF / sliceF);
    if (NC < 1) NC = 1;
    if (NC > B) NC = B;

    float* Qh = (float*)d_ws;
    float* Kh = Qh + (size_t)NC * TE;
    float* Vh = Kh + (size_t)NC * TE;
    float* Zh = Vh + (size_t)NC * TE;
    float* Sh = Zh + (size_t)NC * TE;

    hipMemsetAsync(out, 0, (size_t)B * TE * sizeof(float), stream);

    dim3 blk(256);

    for (int h = 0; h < H; ++h) {
        // Quirky-reshape window: out row i reads Zc flat [i*9216,(i+1)*9216);
        // head h owns flat [h*786432,(h+1)*786432). Bounds multiples of 768.
        const int i_lo = (int)(((long long)h * TE) / HE);
        const long long aShift = (long long)i_lo * HE - (long long)h * TE;

        for (int b0 = 0; b0 < B; b0 += NC) {
            const int nb = (B - b0 < NC) ? (B - b0) : NC;

            // Fused Q/K/V projections: (nb*T x E) @ (E x E), 256x128 core.
            dim3 gp(E / 128, nb * T / 256, 3);
            gemm_qkv<<<gp, blk, 0, stream>>>(x + (long long)b0 * TE,
                WQ + (size_t)h * E * E, WK + (size_t)h * E * E,
                WV + (size_t)h * E * E, Qh, Kh, Vh, E, E, E, E);

            // Scores: Q_b (T x E) @ K_b flat reinterpreted as (E x T), ldb=T.
            dim3 gs(T / 128, T / 128, nb);
            gemm_one<<<gs, blk, 0, stream>>>(Qh, Kh, Sh, E, E, T, T,
                TE, TE, TT, 0, BIG, NOCLIP, 0, 1);

            // Softmax over query axis with 1/sqrt(T) pre-scale (in place).
            col_softmax<<<dim3(T / 64, nb), blk, 0, stream>>>(Sh, T, 0.03125f);

            // Z = A (T x T) @ V_b (T x E)
            dim3 gz(E / 128, T / 128, nb);
            gemm_one<<<gz, blk, 0, stream>>>(Sh, Vh, Zh, T, T, E, E,
                TT, TE, TE, 0, BIG, NOCLIP, 0, 1);

            // Final projection contribution of head h, K-SPLIT x12 + atomics:
            // out_b[i_lo+m,:] += A_h @ WO, A_h[m,k] = Zflat[m*9216+k+aShift]
            dim3 gf(E / 128, 12, nb);   // y = k-chunks (single m-tile)
            gemm_one<<<gf, blk, 0, stream>>>(Zh, WO,
                out + (long long)b0 * TE + (long long)i_lo * E,
                (int)HE, (int)HE, E, E, TE, 0, TE,
                aShift, TE, T - i_lo, 2, 12);
        }
    }
}